// Round 1
// baseline (440.289 us; speedup 1.0000x reference)
//
#include <hip/hip_runtime.h>

// EMAttention2d on MI355X — v1: correctness-first fp16-MFMA pipeline.
// B=16, C=512, H=W=64 (N=4096), K=64, 3 EM iters.
// Key identity: zn-normalization cancels under mu column-L2-norm, so
// mu_b = colnorm_c(yf^T @ z)  (no zn materialization).

typedef _Float16 half_t;
typedef _Float16 half8 __attribute__((ext_vector_type(8)));
typedef float f32x4 __attribute__((ext_vector_type(4)));

#define GLD_LDS(gp, lp) __builtin_amdgcn_global_load_lds( \
    (const __attribute__((address_space(1))) void*)(gp),  \
    (__attribute__((address_space(3))) void*)(lp), 16, 0, 0)

constexpr int CB = 16;       // batch
constexpr int CC = 512;      // channels
constexpr int CN = 4096;     // H*W
constexpr int CKK = 64;      // codebook size K
constexpr long MALL = (long)CB * CN;   // 65536

// ---------------------------------------------------------------------------
// K0: convert weights to fp16; init per-batch muT (K,C) and mu_ck (C,K).
__global__ __launch_bounds__(256) void prep(
    const float* __restrict__ stem_w, const float* __restrict__ head_w,
    const float* __restrict__ mu,
    half_t* __restrict__ swh, half_t* __restrict__ hwh,
    half_t* __restrict__ muT, half_t* __restrict__ muck)
{
  int i = blockIdx.x * 256 + threadIdx.x;   // grid covers C*C = 262144
  swh[i] = (half_t)stem_w[i];
  hwh[i] = (half_t)head_w[i];
  if (i < CC * CKK) {
    int c = i >> 6, k = i & 63;
    half_t v = (half_t)mu[i];               // mu is (C,K) row-major
    for (int b = 0; b < CB; ++b) {
      muT[(long)b * CKK * CC + (long)k * CC + c] = v;
      muck[(long)b * CC * CKK + i] = v;
    }
  }
}

// ---------------------------------------------------------------------------
// Generic tile transpose: in (bz, R, S) [Tin] -> out (bz, S, R) [fp16].
template <typename Tin>
__global__ __launch_bounds__(256) void transpose2(
    const Tin* __restrict__ in, half_t* __restrict__ out, int R, int S)
{
  __shared__ half_t t[64][65];
  const int s0 = blockIdx.x * 64, r0 = blockIdx.y * 64;
  const long bz = blockIdx.z;
  const Tin* ib = in + bz * (long)R * S;
  half_t* ob = out + bz * (long)R * S;
  const int tid = threadIdx.x;
  const int cl = tid & 63, rw = tid >> 6;
#pragma unroll
  for (int it = 0; it < 16; ++it) {
    int r = it * 4 + rw;
    t[cl][r] = (half_t)(float)ib[(long)(r0 + r) * S + s0 + cl];
  }
  __syncthreads();
#pragma unroll
  for (int it = 0; it < 16; ++it) {
    int s = it * 4 + rw;
    ob[(long)(s0 + s) * R + r0 + cl] = t[s][cl];
  }
}

// ---------------------------------------------------------------------------
// Generic fp16 GEMM, A@B^T form:  D[m][n] = sum_k A[m][k]*B[n][k].
// A: (M,K) row-major fp16. B: (Nn,K) row-major fp16. BK=64 per step.
// MODE bit0: +bias[n]; bit1: relu; bit2: atomic fp32 accumulate into Cacc.
template <int BM, int BN, int MODE>
__global__ __launch_bounds__(256) void gemm_abt(
    const half_t* __restrict__ A, const half_t* __restrict__ Bm,
    half_t* __restrict__ Co, float* __restrict__ Cacc,
    const float* __restrict__ bias,
    int M, int Nn, int Kk, int ksplit, long sA, long sB, long sC)
{
  constexpr int FM = BM / 32, FN = BN / 32;
  __shared__ __align__(16) half_t lA[BM * 64];
  __shared__ __align__(16) half_t lB[BN * 64];
  const int tid = threadIdx.x, wid = tid >> 6, lane = tid & 63;
  const int tilesN = Nn / BN;
  const int tm = blockIdx.x / tilesN, tn = blockIdx.x % tilesN;
  const long bz = blockIdx.z;
  const half_t* Ab = A + bz * sA + (long)tm * BM * Kk;
  const half_t* Bb = Bm + bz * sB + (long)tn * BN * Kk;
  const int ksteps = Kk >> 6;
  const int per = ksteps / ksplit;
  const int ks0 = blockIdx.y * per, ks1 = ks0 + per;
  const int wr = wid >> 1, wc = wid & 1;

  f32x4 acc[FM][FN];
#pragma unroll
  for (int i = 0; i < FM; ++i)
#pragma unroll
    for (int j = 0; j < FN; ++j) acc[i][j] = f32x4{0.f, 0.f, 0.f, 0.f};

  for (int ks = ks0; ks < ks1; ++ks) {
    __syncthreads();
    {
      const half_t* ga = Ab + (long)ks * 64;
#pragma unroll
      for (int c = wid; c < BM / 8; c += 4) {
        const half_t* g = ga + (long)(c * 8 + (lane >> 3)) * Kk + (lane & 7) * 8;
        GLD_LDS(g, &lA[c * 512]);
      }
      const half_t* gb = Bb + (long)ks * 64;
#pragma unroll
      for (int c = wid; c < BN / 8; c += 4) {
        const half_t* g = gb + (long)(c * 8 + (lane >> 3)) * Kk + (lane & 7) * 8;
        GLD_LDS(g, &lB[c * 512]);
      }
    }
    __syncthreads();   // compiler emits vmcnt(0) drain before barrier
#pragma unroll
    for (int kk = 0; kk < 2; ++kk) {
      half8 af[FM], bfr[FN];
#pragma unroll
      for (int i = 0; i < FM; ++i)
        af[i] = *(const half8*)&lA[(wr * (BM / 2) + i * 16 + (lane & 15)) * 64 +
                                   kk * 32 + (lane >> 4) * 8];
#pragma unroll
      for (int j = 0; j < FN; ++j)
        bfr[j] = *(const half8*)&lB[(wc * (BN / 2) + j * 16 + (lane & 15)) * 64 +
                                    kk * 32 + (lane >> 4) * 8];
#pragma unroll
      for (int i = 0; i < FM; ++i)
#pragma unroll
        for (int j = 0; j < FN; ++j)
          acc[i][j] = __builtin_amdgcn_mfma_f32_16x16x32_f16(af[i], bfr[j],
                                                             acc[i][j], 0, 0, 0);
    }
  }

#pragma unroll
  for (int j = 0; j < FN; ++j) {
    const int n = tn * BN + wc * (BN / 2) + j * 16 + (lane & 15);
    float bv = 0.f;
    if constexpr (MODE & 1) bv = bias[n];
#pragma unroll
    for (int i = 0; i < FM; ++i) {
      const int mbase = tm * BM + wr * (BM / 2) + i * 16 + ((lane >> 4) << 2);
#pragma unroll
      for (int r = 0; r < 4; ++r) {
        const long idx = bz * sC + (long)(mbase + r) * Nn + n;
        if constexpr ((MODE & 4) != 0) {
          atomicAdd(&Cacc[idx], acc[i][j][r]);
        } else {
          float v = acc[i][j][r] + bv;
          if constexpr ((MODE & 2) != 0) v = fmaxf(v, 0.f);
          Co[idx] = (half_t)v;
        }
      }
    }
  }
}

// ---------------------------------------------------------------------------
// K3: S = Yf @ muT^T (per batch, 128 rows x 64 cols per block), fused rowwise
// softmax (LAMBDA_A = 1), writes z (N,K) and zT (K,N) fp16.
__global__ __launch_bounds__(256) void s_softmax(
    const half_t* __restrict__ Yf, const half_t* __restrict__ muT,
    half_t* __restrict__ z, half_t* __restrict__ zT)
{
  __shared__ __align__(16) union {
    struct { half_t a[128 * 64]; half_t b[64 * 64]; } st;
    struct { float s[128 * 65]; half_t zh[128 * 68]; } p2;
  } sm;
  const int tid = threadIdx.x, wid = tid >> 6, lane = tid & 63;
  const int tm = blockIdx.x;
  const long bz = blockIdx.z;
  const half_t* Ab = Yf + bz * (long)CN * CC + (long)tm * 128 * CC;
  const half_t* Bb = muT + bz * (long)CKK * CC;
  const int wr = wid >> 1, wc = wid & 1;

  f32x4 acc[4][2];
#pragma unroll
  for (int i = 0; i < 4; ++i)
#pragma unroll
    for (int j = 0; j < 2; ++j) acc[i][j] = f32x4{0.f, 0.f, 0.f, 0.f};

  for (int ks = 0; ks < 8; ++ks) {   // Kk = 512
    __syncthreads();
    {
      const half_t* ga = Ab + (long)ks * 64;
#pragma unroll
      for (int c = wid; c < 16; c += 4) {
        const half_t* g = ga + (long)(c * 8 + (lane >> 3)) * CC + (lane & 7) * 8;
        GLD_LDS(g, &sm.st.a[c * 512]);
      }
      const half_t* gb = Bb + (long)ks * 64;
#pragma unroll
      for (int c = wid; c < 8; c += 4) {
        const half_t* g = gb + (long)(c * 8 + (lane >> 3)) * CC + (lane & 7) * 8;
        GLD_LDS(g, &sm.st.b[c * 512]);
      }
    }
    __syncthreads();
#pragma unroll
    for (int kk = 0; kk < 2; ++kk) {
      half8 af[4], bfr[2];
#pragma unroll
      for (int i = 0; i < 4; ++i)
        af[i] = *(const half8*)&sm.st.a[(wr * 64 + i * 16 + (lane & 15)) * 64 +
                                        kk * 32 + (lane >> 4) * 8];
#pragma unroll
      for (int j = 0; j < 2; ++j)
        bfr[j] = *(const half8*)&sm.st.b[(wc * 32 + j * 16 + (lane & 15)) * 64 +
                                         kk * 32 + (lane >> 4) * 8];
#pragma unroll
      for (int i = 0; i < 4; ++i)
#pragma unroll
        for (int j = 0; j < 2; ++j)
          acc[i][j] = __builtin_amdgcn_mfma_f32_16x16x32_f16(af[i], bfr[j],
                                                             acc[i][j], 0, 0, 0);
    }
  }
  __syncthreads();
  // scatter S tile to LDS (fp32)
#pragma unroll
  for (int j = 0; j < 2; ++j)
#pragma unroll
    for (int i = 0; i < 4; ++i)
#pragma unroll
      for (int r = 0; r < 4; ++r) {
        int nl = wc * 32 + j * 16 + (lane & 15);
        int ml = wr * 64 + i * 16 + ((lane >> 4) << 2) + r;
        sm.p2.s[ml * 65 + nl] = acc[i][j][r];
      }
  __syncthreads();
  if (tid < 128) {        // rowwise softmax over 64 cols
    float row[64];
    float mx = -1e30f;
#pragma unroll
    for (int k = 0; k < 64; ++k) { row[k] = sm.p2.s[tid * 65 + k]; mx = fmaxf(mx, row[k]); }
    float sum = 0.f;
#pragma unroll
    for (int k = 0; k < 64; ++k) { row[k] = __expf(row[k] - mx); sum += row[k]; }
    const float inv = 1.f / sum;
#pragma unroll
    for (int k = 0; k < 64; ++k) sm.p2.zh[tid * 68 + k] = (half_t)(row[k] * inv);
  }
  __syncthreads();
  { // z (N,K): rows n, contiguous k
    const int nl = tid >> 1, seg = tid & 1;
    const long base = bz * (long)CN * CKK + (long)(tm * 128 + nl) * CKK + seg * 32;
#pragma unroll
    for (int g = 0; g < 4; ++g) {
      half8 v;
#pragma unroll
      for (int e = 0; e < 8; ++e) v[e] = sm.p2.zh[nl * 68 + seg * 32 + g * 8 + e];
      *(half8*)&z[base + g * 8] = v;
    }
  }
  { // zT (K,N): rows k, contiguous n
    const int k = tid >> 2, seg = tid & 3;
    const long base = bz * (long)CKK * CN + (long)k * CN + tm * 128 + seg * 32;
#pragma unroll
    for (int g = 0; g < 4; ++g) {
      half8 v;
#pragma unroll
      for (int e = 0; e < 8; ++e) v[e] = sm.p2.zh[(seg * 32 + g * 8 + e) * 68 + k];
      *(half8*)&zT[base + g * 8] = v;
    }
  }
}

// ---------------------------------------------------------------------------
// K4b: mu = R / max(||R||_c, 1e-12) per (b,k); write muT (K,C) and mu_ck (C,K).
__global__ __launch_bounds__(64) void mu_norm(
    const float* __restrict__ acc, half_t* __restrict__ muT, half_t* __restrict__ muck)
{
  const int bk = blockIdx.x;           // b*64 + k
  const int b = bk >> 6, k = bk & 63;
  const float* row = acc + (long)bk * CC;
  const int t = threadIdx.x;
  float v[8]; float s = 0.f;
#pragma unroll
  for (int e = 0; e < 8; ++e) { v[e] = row[t * 8 + e]; s += v[e] * v[e]; }
#pragma unroll
  for (int m = 1; m < 64; m <<= 1) s += __shfl_xor(s, m);
  const float inv = 1.f / fmaxf(sqrtf(s), 1e-12f);
  half8 o;
#pragma unroll
  for (int e = 0; e < 8; ++e) o[e] = (half_t)(v[e] * inv);
  *(half8*)&muT[(long)bk * CC + t * 8] = o;
  half_t* mc = muck + (long)b * CC * CKK;
#pragma unroll
  for (int e = 0; e < 8; ++e) mc[(long)(t * 8 + e) * CKK + k] = o[e];
}

// ---------------------------------------------------------------------------
// K7: BN batch stats (sum, sumsq per channel) over all B*N rows of hf (.,C).
__global__ __launch_bounds__(512) void bn_stats(
    const half_t* __restrict__ hf, float* __restrict__ stats)
{
  const int c = threadIdx.x;
  const long r0 = (long)blockIdx.x * 256;
  float s = 0.f, s2 = 0.f;
  for (int i = 0; i < 256; ++i) {
    float v = (float)hf[(r0 + i) * CC + c];
    s += v; s2 += v * v;
  }
  atomicAdd(&stats[c], s);
  atomicAdd(&stats[CC + c], s2);
}

__global__ void bn_param(const float* __restrict__ stats,
                         const float* __restrict__ gamma, const float* __restrict__ beta,
                         float* __restrict__ scsh)
{
  const int c = threadIdx.x;
  const float cnt = 1.f / 65536.f;
  const float mean = stats[c] * cnt;
  const float var = stats[CC + c] * cnt - mean * mean;
  const float sc = gamma[c] * rsqrtf(var + 1e-5f);
  scsh[c] = sc;
  scsh[CC + c] = beta[c] - mean * sc;
}

// ---------------------------------------------------------------------------
// K8: out(B,C,N) = relu( BN(hf)(transposed from (N,C)) + x ).
__global__ __launch_bounds__(256) void bn_final(
    const half_t* __restrict__ hf, const float* __restrict__ x,
    const float* __restrict__ scale, const float* __restrict__ shift,
    float* __restrict__ out)
{
  __shared__ float t[64][65];
  const int n0 = blockIdx.x * 64, c0 = blockIdx.y * 64;
  const long bz = blockIdx.z;
  const half_t* hb = hf + bz * (long)CN * CC;
  const int tid = threadIdx.x, cl = tid & 63, rw = tid >> 6;
#pragma unroll
  for (int it = 0; it < 16; ++it) {
    int n = it * 4 + rw;
    t[cl][n] = (float)hb[(long)(n0 + n) * CC + c0 + cl];   // t[c][n]
  }
  __syncthreads();
  const float* xb = x + bz * (long)CC * CN;
  float* ob = out + bz * (long)CC * CN;
#pragma unroll
  for (int it = 0; it < 16; ++it) {
    int c = it * 4 + rw;
    const float sc = scale[c0 + c], sh = shift[c0 + c];
    const long idx = (long)(c0 + c) * CN + n0 + cl;
    float v = t[c][cl] * sc + sh + xb[idx];
    ob[idx] = fmaxf(v, 0.f);
  }
}

// ---------------------------------------------------------------------------
extern "C" void kernel_launch(void* const* d_in, const int* in_sizes, int n_in,
                              void* d_out, int out_size, void* d_ws, size_t ws_size,
                              hipStream_t stream)
{
  const float* x      = (const float*)d_in[0];
  const float* mu     = (const float*)d_in[1];
  const float* stem_w = (const float*)d_in[2];
  const float* stem_b = (const float*)d_in[3];
  const float* head_w = (const float*)d_in[4];
  const float* head_b = (const float*)d_in[5];
  const float* bn_g   = (const float*)d_in[6];
  const float* bn_b   = (const float*)d_in[7];
  float* out = (float*)d_out;

  const size_t NEED = 214ull << 20;
  if (ws_size < NEED) {   // distinct failure signature instead of OOB scribble
    hipMemsetAsync(d_out, 0, (size_t)out_size * 4, stream);
    return;
  }
  char* ws = (char*)d_ws;
  const long MB = 1 << 20;
  half_t* xT   = (half_t*)(ws);              // 64 MiB ; reused as y2f
  half_t* Yf   = (half_t*)(ws + 64 * MB);    // 64 MiB
  half_t* ycn  = (half_t*)(ws + 128 * MB);   // 64 MiB ; reused as hf
  half_t* z    = (half_t*)(ws + 192 * MB);   // 8 MiB
  half_t* zT   = (half_t*)(ws + 200 * MB);   // 8 MiB
  half_t* muT  = (half_t*)(ws + 208 * MB);   // 1 MiB
  half_t* muck = (half_t*)(ws + 209 * MB);   // 1 MiB
  float* muacc = (float*)(ws + 210 * MB);    // 2 MiB
  half_t* swh  = (half_t*)(ws + 212 * MB);
  half_t* hwh  = (half_t*)(ws + 212 * MB + 512 * 1024);
  float* stats = (float*)(ws + 213 * MB);
  float* scsh  = (float*)(ws + 213 * MB + 8 * 1024);
  half_t* y2f = xT;
  half_t* hf  = ycn;

  prep<<<1024, 256, 0, stream>>>(stem_w, head_w, mu, swh, hwh, muT, muck);
  // xT (B,N,C) <- x (B,C,N)
  transpose2<float><<<dim3(64, 8, 16), 256, 0, stream>>>(x, xT, CC, CN);
  // stem: Yf (B*N, C) = xT @ stem_w^T + stem_b
  gemm_abt<128, 128, 1><<<dim3(2048, 1, 1), 256, 0, stream>>>(
      xT, swh, Yf, nullptr, stem_b, (int)MALL, CC, CC, 1, 0, 0, 0);
  // y_cn (B,C,N) <- Yf (B,N,C)
  transpose2<half_t><<<dim3(8, 64, 16), 256, 0, stream>>>(Yf, ycn, CN, CC);

  for (int it = 0; it < 3; ++it) {
    s_softmax<<<dim3(32, 1, 16), 256, 0, stream>>>(Yf, muT, z, zT);
    hipMemsetAsync(muacc, 0, (size_t)CB * CKK * CC * 4, stream);
    // mu_raw^T (K,C) = zT @ y_cn^T   (reduction over n, split 4, atomics)
    gemm_abt<64, 128, 4><<<dim3(4, 4, 16), 256, 0, stream>>>(
        zT, ycn, nullptr, muacc, nullptr, CKK, CC, CN, 4,
        (long)CKK * CN, (long)CC * CN, (long)CKK * CC);
    mu_norm<<<CB * CKK, 64, 0, stream>>>(muacc, muT, muck);
  }
  // y2f (B,N,C) = relu(z @ mu_ck^T)
  gemm_abt<128, 128, 2><<<dim3(128, 1, 16), 256, 0, stream>>>(
      z, muck, y2f, nullptr, nullptr, CN, CC, CKK, 1,
      (long)CN * CKK, (long)CC * CKK, (long)CN * CC);
  // head: hf (B*N, C) = y2f @ head_w^T + head_b
  gemm_abt<128, 128, 1><<<dim3(2048, 1, 1), 256, 0, stream>>>(
      y2f, hwh, hf, nullptr, head_b, (int)MALL, CC, CC, 1, 0, 0, 0);

  hipMemsetAsync(stats, 0, 2 * CC * 4, stream);
  bn_stats<<<256, 512, 0, stream>>>(hf, stats);
  bn_param<<<1, 512, 0, stream>>>(stats, bn_g, bn_b, scsh);
  bn_final<<<dim3(64, 8, 16), 256, 0, stream>>>(hf, x, scsh, scsh + CC, out);
}